// Round 5
// baseline (400.833 us; speedup 1.0000x reference)
//
#include <hip/hip_runtime.h>

#define NNODES 8192
#define NEDGES 65536

#define K_PACK   0.02209708691f   // 1/sqrt(2048)
#define K_P1SV   0.01804219593f   // 1/(32*sqrt3)
#define K_VVS    0.04419417382f   // 1/sqrt(512)
#define K_VS     0.03608439182f   // 1/(16*sqrt3)
#define K_VVV    0.02551551815f   // K_VS/sqrt2
#define K_DOT    0.57735026919f
#define K_PRELN  0.35355339059f
#define C_EMB    8.4335730689f

typedef unsigned int uint32;
typedef unsigned short ushort16;
typedef __attribute__((ext_vector_type(8))) short short8;
typedef __attribute__((ext_vector_type(4))) float floatx4;

__device__ __forceinline__ float siluf(float x) { return x / (1.0f + __expf(-x)); }
__device__ __forceinline__ float susf(float t) { return t > 0.0f ? __expf(-1.0f / t) : 0.0f; }
__device__ __forceinline__ ushort16 f2bf(float f) {
  uint32 u = __float_as_uint(f);
  return (ushort16)((u + 0x7fffu + ((u >> 16) & 1u)) >> 16);
}
__device__ __forceinline__ float bflo(uint32 v) { return __uint_as_float(v << 16); }
__device__ __forceinline__ float bfhi(uint32 v) { return __uint_as_float(v & 0xffff0000u); }

__device__ __forceinline__ void mlp32(const float* __restrict__ W, const float emb[10],
                                      float* __restrict__ H) {
#pragma unroll
  for (int m = 0; m < 32; ++m) {
    float t = 0.f;
#pragma unroll
    for (int k = 0; k < 10; ++k) t += emb[k] * W[k * 32 + m];
    H[m] = siluf(t);
  }
}

// ---------- prep ----------
__global__ __launch_bounds__(256) void k_prep(
    const float* __restrict__ pos, const int* __restrict__ z, const int* __restrict__ mol,
    const int* __restrict__ esrc, const int* __restrict__ edst,
    const float* __restrict__ Ez, const float* __restrict__ Em,
    const float* __restrict__ W10, const float* __restrict__ W11, const float* __restrict__ W12,
    const float* __restrict__ W20, const float* __restrict__ W21, const float* __restrict__ W22,
    int* __restrict__ combo, ushort16* __restrict__ X0cb, float* __restrict__ sh,
    float* __restrict__ h0, float* __restrict__ h1, float* __restrict__ h2,
    uint32* __restrict__ hb1u, uint32* __restrict__ hb2u,
    ushort16* __restrict__ Bp0, ushort16* __restrict__ Bp1, ushort16* __restrict__ Bp2,
    ushort16* __restrict__ Bpk1, ushort16* __restrict__ Bpk2) {
  int idx = blockIdx.x * 256 + threadIdx.x;
  if (idx < NEDGES) {
    int e = idx;
    int s = esrc[e], d = edst[e];
    float vx = pos[d * 3 + 0] - pos[s * 3 + 0];
    float vy = pos[d * 3 + 1] - pos[s * 3 + 1];
    float vz = pos[d * 3 + 2] - pos[s * 3 + 2];
    float len = sqrtf(vx * vx + vy * vy + vz * vz);
    float inv = 1.7320508076f / fmaxf(len, 1e-9f);
    sh[e * 3 + 0] = vx * inv; sh[e * 3 + 1] = vy * inv; sh[e * 3 + 2] = vz * inv;
    float emb[10];
#pragma unroll
    for (int k = 0; k < 10; ++k) {
      float u = len * 1.1f - (float)(k + 1);
      emb[k] = C_EMB * susf(u + 1.0f) * susf(1.0f - u);
    }
    float H0[32], H1[32], H2[32];
    mlp32(W10, emb, H0);
    mlp32(W11, emb, H1);
    mlp32(W12, emb, H2);
#pragma unroll
    for (int m = 0; m < 32; ++m) {
      h0[(size_t)e * 32 + m] = H0[m];
      h1[(size_t)e * 32 + m] = H1[m];
      h2[(size_t)e * 32 + m] = H2[m];
    }
#pragma unroll
    for (int m = 0; m < 16; ++m) {
      hb1u[(size_t)e * 16 + m] = (uint32)f2bf(H1[2 * m]) | ((uint32)f2bf(H1[2 * m + 1]) << 16);
      hb2u[(size_t)e * 16 + m] = (uint32)f2bf(H2[2 * m]) | ((uint32)f2bf(H2[2 * m + 1]) << 16);
    }
    return;
  }
  idx -= NEDGES;
  if (idx < NNODES) { combo[idx] = z[idx] * 2 + mol[idx]; return; }
  idx -= NNODES;
  if (idx < 16384) {  // X0cb[256][64] bf16
    int c = idx >> 6, j = idx & 63;
    float v = 0.f;
    if (c < 200) {
      int zz = c >> 1, mm = c & 1;
      v = (j < 48) ? Ez[zz * 48 + j] : Em[mm * 16 + (j - 48)];
    }
    X0cb[idx] = f2bf(v);
    return;
  }
  idx -= 16384;
  if (idx < 81920) {  // Bp0[tile(80)][kh(2)][lane][j8], K=64
    int tile = idx >> 10; int r = idx & 1023;
    int kh = r >> 9; int rr = r & 511;
    int lane = rr >> 3, j = rr & 7;
    int k = kh * 32 + (lane >> 4) * 8 + j;
    int n = tile * 16 + (lane & 15);
    int c = n >> 5, m = n & 31;
    int col = (c < 32) ? (k * 32 + c) : (2048 + k * 8 + (c - 32));
    Bp0[idx] = f2bf(W20[m * 2560 + col] * K_PACK);
    return;
  }
  idx -= 81920;
  if (idx < 40960) {  // Bp1[tile(80)][lane][j8], K=32
    int tile = idx >> 9; int rr = idx & 511;
    int lane = rr >> 3, j = rr & 7;
    int k = (lane >> 4) * 8 + j;
    int n = tile * 16 + (lane & 15);
    int c = n >> 5, m = n & 31;
    float v = (c < 32) ? W21[m * 1664 + k * 32 + c] * K_PACK
                       : W21[m * 1664 + 1280 + k * 8 + (c - 32)] * K_P1SV;
    Bp1[idx] = f2bf(v);
    return;
  }
  idx -= 40960;
  if (idx < 16384) {  // Bp2[tile(32)][lane][j8], K=32
    int tile = idx >> 9; int rr = idx & 511;
    int lane = rr >> 3, j = rr & 7;
    int k = (lane >> 4) * 8 + j;
    int n = tile * 16 + (lane & 15);
    int c = n >> 5, m = n & 31;
    Bp2[idx] = f2bf(W22[m * 640 + k * 16 + c] * K_PACK);
    return;
  }
  idx -= 16384;
  if (idx < 12288) {  // Bpk1[tile(24)][lane][j8]: Wcat1[k=m][n=384]
    int tile = idx >> 9; int rr = idx & 511;
    int lane = rr >> 3, jj = rr & 7;
    int k = (lane >> 4) * 8 + jj;
    int n = tile * 16 + (lane & 15);
    float v;
    if (n < 256) {        // vvs: w = n>>3 (32), u = n&7
      v = W21[k * 1664 + 1024 + (n & 7) * 32 + (n >> 3)] * K_VVS;
    } else if (n < 320) { // vs
      int nn = n - 256;
      v = W21[k * 1664 + 1536 + (nn & 7) * 8 + (nn >> 3)] * K_VS;
    } else {              // vvv
      int nn = n - 320;
      v = W21[k * 1664 + 1600 + (nn & 7) * 8 + (nn >> 3)] * K_VVV;
    }
    Bpk1[idx] = f2bf(v);
    return;
  }
  idx -= 12288;
  {  // Bpk2[tile(8)][lane][j8]: Wcat2[k=m][n=128]
    int tile = idx >> 9; int rr = idx & 511;
    int lane = rr >> 3, jj = rr & 7;
    int k = (lane >> 4) * 8 + jj;
    int n = tile * 16 + (lane & 15);
    Bpk2[idx] = f2bf(W22[k * 640 + 512 + (n & 7) * 16 + (n >> 3)] * K_VVS);
  }
}

// ---------- MFMA GEMM ----------
__global__ __launch_bounds__(256) void k_gemm_mfma(
    const ushort16* __restrict__ A, const ushort16* __restrict__ Bp, ushort16* __restrict__ C,
    int N, int K) {
  int wave = threadIdx.x >> 6, lane = threadIdx.x & 63;
  int m0 = blockIdx.x * 64 + wave * 16;
  int n0 = blockIdx.y * 64;
  int row = lane & 15, q = lane >> 4;
  int nkh = K >> 5;
  floatx4 acc[4];
  floatx4 zero = {0.f, 0.f, 0.f, 0.f};
#pragma unroll
  for (int t = 0; t < 4; ++t) acc[t] = zero;
  for (int kh = 0; kh < nkh; ++kh) {
    short8 a = *reinterpret_cast<const short8*>(A + (size_t)(m0 + row) * K + kh * 32 + q * 8);
#pragma unroll
    for (int t = 0; t < 4; ++t) {
      int T = (n0 >> 4) + t;
      short8 b = *reinterpret_cast<const short8*>(Bp + ((size_t)T * nkh + kh) * 512 + lane * 8);
      acc[t] = __builtin_amdgcn_mfma_f32_16x16x32_bf16(a, b, acc[t], 0, 0, 0);
    }
  }
  int colb = n0 + row;
#pragma unroll
  for (int t = 0; t < 4; ++t)
#pragma unroll
    for (int r = 0; r < 4; ++r)
      C[(size_t)(m0 + q * 4 + r) * N + colb + t * 16] = f2bf(acc[t][r]);
}

// ---------- block-0 P-gather ----------
__global__ __launch_bounds__(256) void k_edgeP56(
    const int* __restrict__ rowmap, const int* __restrict__ esrc, const int* __restrict__ edst,
    const float* __restrict__ sh, const float* __restrict__ h,
    const ushort16* __restrict__ Pb, float* __restrict__ acc) {
  int e = __builtin_amdgcn_readfirstlane(blockIdx.x * 4 + (threadIdx.x >> 6));
  int lane = threadIdx.x & 63;
  int s = esrc[e], d = edst[e];
  int row = rowmap ? rowmap[s] : s;
  float sh0 = sh[e * 3 + 0], sh1 = sh[e * 3 + 1], sh2 = sh[e * 3 + 2];
  int c; float mult;
  if (lane < 32) { c = lane; mult = 1.0f; }
  else if (lane < 56) {
    int l = lane - 32; int v = l / 3; int i = l - v * 3;
    c = 32 + v;
    mult = (i == 0) ? sh0 : (i == 1 ? sh1 : sh2);
  } else { c = 0; mult = 0.0f; }
  const float* hp = h + (size_t)e * 32;
  const uint4* Pp = reinterpret_cast<const uint4*>(Pb + (size_t)row * 1280 + c * 32);
  float a = 0.f;
#pragma unroll
  for (int qq = 0; qq < 4; ++qq) {
    uint4 pv = Pp[qq];
    const float* hq = hp + qq * 8;
    a += bflo(pv.x) * hq[0] + bfhi(pv.x) * hq[1];
    a += bflo(pv.y) * hq[2] + bfhi(pv.y) * hq[3];
    a += bflo(pv.z) * hq[4] + bfhi(pv.z) * hq[5];
    a += bflo(pv.w) * hq[6] + bfhi(pv.w) * hq[7];
  }
  if (lane < 56) atomicAdd(&acc[(size_t)d * 56 + lane], a * mult);
}

// ---------- block-1 fused edge kernel: 16 edges/wave, MFMA wgen + P-gather ----------
// LDS per wave (floats): dot[0,128) xv4[128,640) cr4[640,1152) msgW[1152,2048) msgP[2048,2944)
__global__ __launch_bounds__(256) void k_b1(
    const int* __restrict__ esrc, const int* __restrict__ edst, const float* __restrict__ sh,
    const float* __restrict__ h, const ushort16* __restrict__ hb,
    const float* __restrict__ xv, const ushort16* __restrict__ Pb,
    const ushort16* __restrict__ Bpk, float* __restrict__ acc) {
  __shared__ float lds[4][2944];
  int wvi = threadIdx.x >> 6;
  int lane = threadIdx.x & 63;
  int wid = __builtin_amdgcn_readfirstlane(blockIdx.x * 4 + wvi);
  int e0 = wid * 16;
  float* L = &lds[wvi][0];

  // ---- staging: dot / xv / cr ----
  {
    int el = lane & 15, u0 = (lane >> 4) * 2;
    int e = e0 + el;
    int s = esrc[e];
    float s0 = sh[e * 3 + 0], s1 = sh[e * 3 + 1], s2 = sh[e * 3 + 2];
    const float* xp = xv + (size_t)s * 24 + u0 * 3;
    float a0 = xp[0], a1 = xp[1], a2 = xp[2], b0 = xp[3], b1 = xp[4], b2 = xp[5];
    L[el * 8 + u0] = K_DOT * (a0 * s0 + a1 * s1 + a2 * s2);
    L[el * 8 + u0 + 1] = K_DOT * (b0 * s0 + b1 * s1 + b2 * s2);
    float4 xa = {a0, a1, a2, 0.f}, xb = {b0, b1, b2, 0.f};
    *(float4*)&L[128 + (el * 8 + u0) * 4] = xa;
    *(float4*)&L[128 + (el * 8 + u0 + 1) * 4] = xb;
    float4 ca = {a1 * s2 - a2 * s1, a2 * s0 - a0 * s2, a0 * s1 - a1 * s0, 0.f};
    float4 cb = {b1 * s2 - b2 * s1, b2 * s0 - b0 * s2, b0 * s1 - b1 * s0, 0.f};
    *(float4*)&L[640 + (el * 8 + u0) * 4] = ca;
    *(float4*)&L[640 + (el * 8 + u0 + 1) * 4] = cb;
  }
  __builtin_amdgcn_wave_barrier();

  // ---- per-lane epilogue operands + A fragment ----
  int q = lane >> 4, u = lane & 7, wlo = (lane >> 3) & 1;
  short8 afrag = *reinterpret_cast<const short8*>(hb + (size_t)(e0 + (lane & 15)) * 32 + q * 8);
  float dt[4], xvv[4][3], crr[4][3];
#pragma unroll
  for (int r = 0; r < 4; ++r) {
    int row = q * 4 + r;
    dt[r] = L[row * 8 + u];
    float4 xt = *(float4*)&L[128 + (row * 8 + u) * 4];
    float4 ct = *(float4*)&L[640 + (row * 8 + u) * 4];
    xvv[r][0] = xt.x; xvv[r][1] = xt.y; xvv[r][2] = xt.z;
    crr[r][0] = ct.x; crr[r][1] = ct.y; crr[r][2] = ct.z;
  }
  const short8* B8 = reinterpret_cast<const short8*>(Bpk);
  floatx4 zero = {0.f, 0.f, 0.f, 0.f};

  // ---- es tiles (vvs): wgen cols n = w*8+u, w<32 ----
#pragma unroll
  for (int t = 0; t < 16; ++t) {
    short8 b = B8[t * 64 + lane];
    floatx4 c = __builtin_amdgcn_mfma_f32_16x16x32_bf16(afrag, b, zero, 0, 0, 0);
    float v[4];
#pragma unroll
    for (int r = 0; r < 4; ++r) v[r] = c[r] * dt[r];
#pragma unroll
    for (int off = 1; off < 8; off <<= 1)
#pragma unroll
      for (int r = 0; r < 4; ++r) v[r] += __shfl_xor(v[r], off, 64);
    if (u == 0) {
      int w = t * 2 + wlo;
#pragma unroll
      for (int r = 0; r < 4; ++r) L[1152 + (q * 4 + r) * 56 + w] = v[r];
    }
  }
  // ---- ev tiles (vs + vvv): w<8, ch = 32 + w*3 + i ----
#pragma unroll
  for (int tt = 0; tt < 4; ++tt) {
    short8 bv = B8[(16 + tt) * 64 + lane];
    short8 bc = B8[(20 + tt) * 64 + lane];
    floatx4 cv = __builtin_amdgcn_mfma_f32_16x16x32_bf16(afrag, bv, zero, 0, 0, 0);
    floatx4 cc = __builtin_amdgcn_mfma_f32_16x16x32_bf16(afrag, bc, zero, 0, 0, 0);
#pragma unroll
    for (int i = 0; i < 3; ++i) {
      float v[4];
#pragma unroll
      for (int r = 0; r < 4; ++r) v[r] = cv[r] * xvv[r][i] + cc[r] * crr[r][i];
#pragma unroll
      for (int off = 1; off < 8; off <<= 1)
#pragma unroll
        for (int r = 0; r < 4; ++r) v[r] += __shfl_xor(v[r], off, 64);
      if (u == 0) {
        int w = tt * 2 + wlo;
#pragma unroll
        for (int r = 0; r < 4; ++r) L[1152 + (q * 4 + r) * 56 + 32 + w * 3 + i] = v[r];
      }
    }
  }

  // ---- P-gather part (output channel = lane; P row = cch) ----
  int cch, isel;
  if (lane < 32) { cch = lane; isel = -1; }
  else if (lane < 56) { int l = lane - 32; int vv = l / 3; isel = l - vv * 3; cch = 32 + vv; }
  else { cch = 0; isel = -1; }
  for (int el = 0; el < 16; ++el) {
    int e = e0 + el;
    int s = __builtin_amdgcn_readfirstlane(esrc[e]);
    float s0 = sh[e * 3 + 0], s1 = sh[e * 3 + 1], s2 = sh[e * 3 + 2];
    float mult = (lane < 32) ? 1.f : (isel == 0 ? s0 : (isel == 1 ? s1 : s2));
    const uint4* Pp = reinterpret_cast<const uint4*>(Pb + (size_t)s * 1280 + cch * 32);
    const float* hp = h + (size_t)e * 32;
    float a = 0.f;
#pragma unroll
    for (int qq = 0; qq < 4; ++qq) {
      uint4 pv = Pp[qq];
      const float* hq = hp + qq * 8;
      a += bflo(pv.x) * hq[0] + bfhi(pv.x) * hq[1];
      a += bflo(pv.y) * hq[2] + bfhi(pv.y) * hq[3];
      a += bflo(pv.z) * hq[4] + bfhi(pv.z) * hq[5];
      a += bflo(pv.w) * hq[6] + bfhi(pv.w) * hq[7];
    }
    if (lane < 56) L[2048 + el * 56 + lane] = a * mult;  // FIXED: index by output channel (lane)
  }
  __builtin_amdgcn_wave_barrier();

  // ---- single atomic phase: lane -> edge lane>>2, 14 channels ----
  {
    int el = lane >> 2;
    int d = edst[e0 + el];
    int c0 = (lane & 3) * 14;
    float* ap = acc + (size_t)d * 56;
#pragma unroll
    for (int k = 0; k < 14; ++k) {
      int ch = c0 + k;
      atomicAdd(ap + ch, L[1152 + el * 56 + ch] + L[2048 + el * 56 + ch]);
    }
  }
}

// ---------- block-2 fused edge kernel ----------
// LDS per wave: dot[0,128) msgW[128,384) msgP[384,640)
__global__ __launch_bounds__(256) void k_b2(
    const int* __restrict__ esrc, const int* __restrict__ edst, const float* __restrict__ sh,
    const float* __restrict__ h, const ushort16* __restrict__ hb,
    const float* __restrict__ xv, const ushort16* __restrict__ Pb,
    const ushort16* __restrict__ Bpk, float* __restrict__ acc) {
  __shared__ float lds[4][640];
  int wvi = threadIdx.x >> 6;
  int lane = threadIdx.x & 63;
  int wid = __builtin_amdgcn_readfirstlane(blockIdx.x * 4 + wvi);
  int e0 = wid * 16;
  float* L = &lds[wvi][0];

  {
    int el = lane & 15, u0 = (lane >> 4) * 2;
    int e = e0 + el;
    int s = esrc[e];
    float s0 = sh[e * 3 + 0], s1 = sh[e * 3 + 1], s2 = sh[e * 3 + 2];
    const float* xp = xv + (size_t)s * 24 + u0 * 3;
    L[el * 8 + u0] = K_DOT * (xp[0] * s0 + xp[1] * s1 + xp[2] * s2);
    L[el * 8 + u0 + 1] = K_DOT * (xp[3] * s0 + xp[4] * s1 + xp[5] * s2);
  }
  __builtin_amdgcn_wave_barrier();

  int q = lane >> 4, u = lane & 7, wlo = (lane >> 3) & 1;
  short8 afrag = *reinterpret_cast<const short8*>(hb + (size_t)(e0 + (lane & 15)) * 32 + q * 8);
  float dt[4];
#pragma unroll
  for (int r = 0; r < 4; ++r) dt[r] = L[(q * 4 + r) * 8 + u];
  const short8* B8 = reinterpret_cast<const short8*>(Bpk);
  floatx4 zero = {0.f, 0.f, 0.f, 0.f};
#pragma unroll
  for (int t = 0; t < 8; ++t) {
    short8 b = B8[t * 64 + lane];
    floatx4 c = __builtin_amdgcn_mfma_f32_16x16x32_bf16(afrag, b, zero, 0, 0, 0);
    float v[4];
#pragma unroll
    for (int r = 0; r < 4; ++r) v[r] = c[r] * dt[r];
#pragma unroll
    for (int off = 1; off < 8; off <<= 1)
#pragma unroll
      for (int r = 0; r < 4; ++r) v[r] += __shfl_xor(v[r], off, 64);
    if (u == 0) {
      int w = t * 2 + wlo;
#pragma unroll
      for (int r = 0; r < 4; ++r) L[128 + (q * 4 + r) * 16 + w] = v[r];
    }
  }

  // P-part: 4 edges per iter, lane=(q: edge, w16: channel)
  int w16 = lane & 15;
#pragma unroll
  for (int el4 = 0; el4 < 4; ++el4) {
    int el = el4 * 4 + q;
    int e = e0 + el;
    int s = esrc[e];
    const uint4* Pp = reinterpret_cast<const uint4*>(Pb + (size_t)s * 512 + w16 * 32);
    const float* hp = h + (size_t)e * 32;
    float a = 0.f;
#pragma unroll
    for (int qq = 0; qq < 4; ++qq) {
      uint4 pv = Pp[qq];
      const float* hq = hp + qq * 8;
      a += bflo(pv.x) * hq[0] + bfhi(pv.x) * hq[1];
      a += bflo(pv.y) * hq[2] + bfhi(pv.y) * hq[3];
      a += bflo(pv.z) * hq[4] + bfhi(pv.z) * hq[5];
      a += bflo(pv.w) * hq[6] + bfhi(pv.w) * hq[7];
    }
    L[384 + el * 16 + w16] = a;
  }
  __builtin_amdgcn_wave_barrier();

  {
    int el = lane >> 2;
    int d = edst[e0 + el];
    int c0 = (lane & 3) * 4;
    float* ap = acc + (size_t)d * 16;
#pragma unroll
    for (int k = 0; k < 4; ++k) {
      int ch = c0 + k;
      atomicAdd(ap + ch, L[128 + el * 16 + ch] + L[384 + el * 16 + ch]);
    }
  }
}

// ---------- LayerNorm ----------
__global__ __launch_bounds__(256) void k_ln(
    const float* __restrict__ acc, const float* __restrict__ g, const float* __restrict__ b,
    ushort16* __restrict__ xsb, float* __restrict__ xvf, float* __restrict__ outf, int D,
    float* __restrict__ zbuf, int zn) {
  if (zbuf) {
    int gt = blockIdx.x * 256 + threadIdx.x;
    int stride = gridDim.x * 256;
    for (int i = gt; i < zn; i += stride) zbuf[i] = 0.f;
  }
  int n = __builtin_amdgcn_readfirstlane(blockIdx.x * 4 + (threadIdx.x >> 6));
  int lane = threadIdx.x & 63;
  float v = (lane < D) ? acc[(size_t)n * D + lane] * K_PRELN : 0.f;
  float sm = v, sq = v * v;
#pragma unroll
  for (int off = 32; off > 0; off >>= 1) {
    sm += __shfl_xor(sm, off, 64);
    sq += __shfl_xor(sq, off, 64);
  }
  float invD = 1.0f / (float)D;
  float mean = sm * invD;
  float var = sq * invD - mean * mean;
  float rs = rsqrtf(var + 1e-5f);
  float r = (v - mean) * rs * g[lane < D ? lane : 0] + b[lane < D ? lane : 0];
  if (outf) {
    if (lane < D) outf[(size_t)n * D + lane] = r;
  } else {
    if (lane < 32) xsb[(size_t)n * 32 + lane] = f2bf(r);
    else if (lane < 56) xvf[(size_t)n * 24 + lane - 32] = r;
  }
}

extern "C" void kernel_launch(void* const* d_in, const int* in_sizes, int n_in,
                              void* d_out, int out_size, void* d_ws, size_t ws_size,
                              hipStream_t stream) {
  const float* pos = (const float*)d_in[0];
  const int* z = (const int*)d_in[1];
  const int* mol = (const int*)d_in[2];
  const int* esrc = (const int*)d_in[3];
  const int* edst = (const int*)d_in[4];
  const float* Ez = (const float*)d_in[5];
  const float* Em = (const float*)d_in[6];
  const float* b0W1 = (const float*)d_in[7];
  const float* b0W2 = (const float*)d_in[8];
  const float* b0g = (const float*)d_in[9];
  const float* b0b = (const float*)d_in[10];
  const float* b1W1 = (const float*)d_in[11];
  const float* b1W2 = (const float*)d_in[12];
  const float* b1g = (const float*)d_in[13];
  const float* b1b = (const float*)d_in[14];
  const float* b2W1 = (const float*)d_in[15];
  const float* b2W2 = (const float*)d_in[16];
  const float* b2g = (const float*)d_in[17];
  const float* b2b = (const float*)d_in[18];
  float* out = (float*)d_out;

  float* ws = (float*)d_ws;
  size_t o = 0;
  int* combo = (int*)(ws + o); o += NNODES;
  ushort16* X0cb = (ushort16*)(ws + o); o += 8192;
  ushort16* xs1b = (ushort16*)(ws + o); o += 131072;
  float* xv1 = ws + o; o += (size_t)NNODES * 24;
  float* h0 = ws + o; o += (size_t)NEDGES * 32;     // acc1 aliases h0
  float* h1 = ws + o; o += (size_t)NEDGES * 32;
  float* h2 = ws + o; o += (size_t)NEDGES * 32;
  uint32* hb1u = (uint32*)(ws + o); o += (size_t)NEDGES * 16;
  uint32* hb2u = (uint32*)(ws + o); o += (size_t)NEDGES * 16;
  float* shb = ws + o; o += (size_t)NEDGES * 3;
  ushort16* Bp0 = (ushort16*)(ws + o); o += 40960;
  ushort16* Bp1 = (ushort16*)(ws + o); o += 20480;
  ushort16* Bp2 = (ushort16*)(ws + o); o += 8192;
  ushort16* Bpk1 = (ushort16*)(ws + o); o += 6144;
  ushort16* Bpk2 = (ushort16*)(ws + o); o += 2048;
  ushort16* P12 = (ushort16*)(ws + o); o += (size_t)NNODES * 640;
  float* acc0 = ws + o; o += (size_t)NNODES * 56;
  float* acc2 = ws + o; o += (size_t)NNODES * 16;

  ushort16* P0c = P12;
  float* acc1 = h0;
  ushort16* xs2b = xs1b;
  float* xv2 = xv1;
  ushort16* hb1 = (ushort16*)hb1u;
  ushort16* hb2 = (ushort16*)hb2u;

  hipMemsetAsync(acc0, 0, (size_t)(NNODES * 56 + NNODES * 16) * sizeof(float), stream);

  k_prep<<<960, 256, 0, stream>>>(pos, z, mol, esrc, edst, Ez, Em,
                                  b0W1, b1W1, b2W1, b0W2, b1W2, b2W2,
                                  combo, X0cb, shb, h0, h1, h2, hb1u, hb2u,
                                  Bp0, Bp1, Bp2, Bpk1, Bpk2);

  // block 0
  k_gemm_mfma<<<dim3(4, 20), 256, 0, stream>>>(X0cb, Bp0, P0c, 1280, 64);
  k_edgeP56<<<16384, 256, 0, stream>>>(combo, esrc, edst, shb, h0, P0c, acc0);
  k_ln<<<2048, 256, 0, stream>>>(acc0, b0g, b0b, xs1b, xv1, nullptr, 56, acc1, NNODES * 56);

  // block 1 (fused P-gather + MFMA W-paths)
  k_gemm_mfma<<<dim3(128, 20), 256, 0, stream>>>(xs1b, Bp1, P12, 1280, 32);
  k_b1<<<1024, 256, 0, stream>>>(esrc, edst, shb, h1, hb1, xv1, P12, Bpk1, acc1);
  k_ln<<<2048, 256, 0, stream>>>(acc1, b1g, b1b, xs2b, xv2, nullptr, 56, nullptr, 0);

  // block 2 (fused)
  k_gemm_mfma<<<dim3(128, 8), 256, 0, stream>>>(xs2b, Bp2, P12, 512, 32);
  k_b2<<<1024, 256, 0, stream>>>(esrc, edst, shb, h2, hb2, xv2, P12, Bpk2, acc2);
  k_ln<<<2048, 256, 0, stream>>>(acc2, b2g, b2b, nullptr, nullptr, out, 16, nullptr, 0);
}